// Round 14
// baseline (360.675 us; speedup 1.0000x reference)
//
#include <hip/hip_runtime.h>
#include <stdint.h>

// ---------------------------------------------------------------------------
// Fast math helpers.
// ---------------------------------------------------------------------------
__device__ __forceinline__ float fast_exp(float x) {
  return __builtin_amdgcn_exp2f(x * 1.4426950408889634f);
}
__device__ __forceinline__ float fast_rcp(float x) {
  return __builtin_amdgcn_rcpf(x);
}
__device__ __forceinline__ float fast_cos(float x) {
  // v_cos takes revolutions; v_fract does the range reduction.
  return __builtin_amdgcn_cosf(__builtin_amdgcn_fractf(x * 0.15915494309189535f));
}
__device__ __forceinline__ float fast_sigmoid(float x) {
  return fast_rcp(1.0f + fast_exp(-x));
}
__device__ __forceinline__ float fast_tanh(float x) {
  return 1.0f - 2.0f * fast_rcp(1.0f + fast_exp(2.0f * x));
}
// sigmoid on [-1,1]: 0.5 + x/4 - x^3/48 + x^5/480 - 17x^7/80640 (err ~2e-5)
__device__ __forceinline__ float sigmoid_poly(float x) {
  float x2 = x * x;
  float p = fmaf(fmaf(fmaf(-2.1085373e-4f, x2, 2.0833334e-3f), x2,
                      -2.0833334e-2f), x2, 0.25f);
  return fmaf(x, p, 0.5f);
}
// tanh Pade(5,4): err <1e-6 @|x|<=1, <1.3e-4 @|x|<=2.5 (cell state bound ~2.1)
__device__ __forceinline__ float tanh_pade(float x) {
  float x2 = x * x;
  float num = x * fmaf(x2 + 105.f, x2, 945.f);
  float den = fmaf(fmaf(15.f, x2, 420.f), x2, 945.f);
  return num * fast_rcp(den);
}

// Cross-lane XOR exchange within each 4-lane quad via DPP quad_perm
// (update_dpp, tied-old operand — verified correct R7; ~4cy VALU).
template <int CTRL>
__device__ __forceinline__ float dppf(float v) {
  return __int_as_float(__builtin_amdgcn_update_dpp(
      0, __float_as_int(v), CTRL, 0xf, 0xf, true));
}
#define QP_XOR1 0xB1  // [1,0,3,2]
#define QP_XOR2 0x4E  // [2,3,0,1]
#define QP_XOR3 0x1B  // [3,2,1,0]

// ---------------------------------------------------------------------------
// FUSED producer/consumer launch (one kernel, two block roles):
//   blocks [0, nscan)        : scan blocks (1 wave, sequential LSTM over t)
//   blocks [nscan, nscan+NG) : gemm blocks (1 wave, 64 rows = one t-plane part)
// gemm blocks publish plane completion via ctr[t] (threadfence + atomicAdd,
// agent scope — Guideline 16); scan blocks acquire-poll ctr before
// prefetching planes. Wall = max(gemm, scan) instead of gemm + scan.
// Evidence base: R7/R10 ledger — warm gemm ~24-26us (near 21us HBM floor),
// scan ~43us chain-bound (R7-R12: load delivery changes all neutral).
// NO register state across barriers anywhere (R4/R13 spill trap).
// ---------------------------------------------------------------------------
__global__ __launch_bounds__(64) void qlstm_fused_pc(
    const float* __restrict__ x,
    const float* __restrict__ Wf, const float* __restrict__ bf,
    const float* __restrict__ Wi, const float* __restrict__ bi,
    const float* __restrict__ Wu, const float* __restrict__ bu,
    const float* __restrict__ Wo, const float* __restrict__ bo,
    const float* __restrict__ thf, const float* __restrict__ thi,
    const float* __restrict__ thu, const float* __restrict__ tho,
    float* __restrict__ Z, unsigned int* __restrict__ ctr,
    float* __restrict__ out,
    long long rows, int B, int D, int T, int nscan)
{
  __shared__ float tile[64][36];  // gemm role only (9KB; scan blocks idle it)
  const int tid = threadIdx.x;
  const int ldw = D + 4;

  if ((int)blockIdx.x >= nscan) {
    // =================== gemm role (R10's proven G64) ====================
    const long long base = (long long)(blockIdx.x - nscan) * 64;
    const long long r = base + tid;
    const float* Ws[4] = {Wf, Wi, Wu, Wo};
    const float* bs[4] = {bf, bi, bu, bo};
    const float* ts[4] = {thf, thi, thu, tho};

    float acc[12];
#pragma unroll
    for (int g = 0; g < 4; ++g) {
      acc[g * 3 + 0] = bs[g][0] + ts[g][0];  // theta0 folded
      acc[g * 3 + 1] = bs[g][1];
      acc[g * 3 + 2] = bs[g][3] + ts[g][3];  // theta3 folded
    }

    const int nkc = D >> 5;
    for (int kc = 0; kc < nkc; ++kc) {
#pragma unroll
      for (int i = 0; i < 8; ++i) {
        int f = i * 64 + tid;
        int row = f >> 3, col = (f & 7) * 4;
        float4 v = *(const float4*)(x + (base + row) * (long long)D + kc * 32 + col);
        *(float4*)&tile[row][col] = v;
      }
      __syncthreads();
#pragma unroll
      for (int k = 0; k < 32; k += 4) {
        float4 xv = *(float4*)&tile[tid][k];
#pragma unroll
        for (int g = 0; g < 4; ++g) {
#pragma unroll
          for (int jj = 0; jj < 3; ++jj) {
            int row2 = (jj == 2) ? 3 : jj;
            const float* wp = Ws[g] + row2 * ldw + kc * 32 + k;  // uniform -> s_load
            acc[g * 3 + jj] += xv.x * wp[0] + xv.y * wp[1] + xv.z * wp[2] + xv.w * wp[3];
          }
        }
      }
      __syncthreads();
    }

    float* zp = Z + r * 16;  // [t][b][gate][4] layout
#pragma unroll
    for (int g = 0; g < 4; ++g) {
      *(float4*)(zp + g * 4) =
          make_float4(acc[g * 3 + 0], acc[g * 3 + 1], acc[g * 3 + 2], 0.f);
    }
    // publish: this block's 64 rows are all within plane t = base/B
    __threadfence();  // per-lane agent fence: Z stores visible device-wide
    if (tid == 0) {
      int t = (int)(base / B);
      __hip_atomic_fetch_add(&ctr[t], 1u, __ATOMIC_RELAXED,
                             __HIP_MEMORY_SCOPE_AGENT);
    }
    return;
  }

  // ===================== scan role (R10's register pipeline) =====================
  const int gid = blockIdx.x * 64 + tid;
  const int b = gid >> 2, q = gid & 3;
  if (b >= B) return;
  const unsigned int target = (unsigned int)(B >> 6);  // gemm blocks per plane

  const float* Wg = (q == 0) ? Wf : (q == 1) ? Wi : (q == 2) ? Wu : Wo;
  const float* th = (q == 0) ? thf : (q == 1) ? thi : (q == 2) ? thu : tho;
  const float ct1 = fast_cos(th[1]);
  const float m2c = fast_cos(th[2]);

  float wh[3][4];
#pragma unroll
  for (int jj = 0; jj < 3; ++jj) {
    int row = (jj == 2) ? 3 : jj;
#pragma unroll
    for (int d = 0; d < 4; ++d)
      wh[jj][d] = Wg[row * ldw + D + (q ^ d)];
  }
  const bool e0 = ((q & 1) == 0);
  const bool e1 = ((q & 2) == 0);

  float h = 0.f, c = 0.f;

  const float* Zlane = Z + (size_t)gid * 4;
  const size_t tstr = (size_t)16 * B;
  const size_t pstr = (size_t)4 * B;
  float* hx  = out + (size_t)T * B * 4;
  float* cxp = hx + (size_t)B * 4;

  auto wait_plane = [&](int t) {
    while (__hip_atomic_load(&ctr[t], __ATOMIC_ACQUIRE,
                             __HIP_MEMORY_SCOPE_AGENT) < target) {
      __builtin_amdgcn_s_sleep(8);
    }
  };
  auto ld1 = [&](int t) -> float4 {
    return *(const float4*)(Zlane + (size_t)t * tstr);
  };

  auto step = [&](float4 zv, int t) {
    float z0 = zv.x, z1 = zv.y, z2 = zv.z;
    float h1 = dppf<QP_XOR1>(h);
    float h2 = dppf<QP_XOR2>(h);
    float h3 = dppf<QP_XOR3>(h);
    float a0 = fmaf(wh[0][0], h, fmaf(wh[0][1], h1, fmaf(wh[0][2], h2, fmaf(wh[0][3], h3, z0))));
    float a1 = fmaf(wh[1][0], h, fmaf(wh[1][1], h1, fmaf(wh[1][2], h2, fmaf(wh[1][3], h3, z1))));
    float a2 = fmaf(wh[2][0], h, fmaf(wh[2][1], h1, fmaf(wh[2][2], h2, fmaf(wh[2][3], h3, z2))));
    float m0 = fast_cos(a0);
    float m1 = ct1 * fast_cos(a1);
    float m3 = fast_cos(a2);
    float m01 = m0 * m1, m23 = m2c * m3;
    float g0 = m1 * m23;
    float g1 = m01;
    float g2 = m01 * m2c;
    float g3 = m01 * m23;
    float x0 = dppf<QP_XOR1>(g0);
    float x1 = dppf<QP_XOR1>(g1);
    float x2 = dppf<QP_XOR1>(g2);
    float x3 = dppf<QP_XOR1>(g3);
    float s0 = e0 ? g0 : x1;
    float s1 = e0 ? x0 : g1;
    float s2 = e0 ? g2 : x3;
    float s3 = e0 ? x2 : g3;
    float y0 = dppf<QP_XOR2>(s0);
    float y1 = dppf<QP_XOR2>(s1);
    float y2 = dppf<QP_XOR2>(s2);
    float y3 = dppf<QP_XOR2>(s3);
    float wf_ = e1 ? s0 : y2;
    float wi_ = e1 ? s1 : y3;
    float wu_ = e1 ? y0 : s2;
    float wo_ = e1 ? y1 : s3;
    float fg = sigmoid_poly(wf_);
    float ig = sigmoid_poly(wi_);
    float ug = tanh_pade(wu_);
    float og = sigmoid_poly(wo_);
    c = fmaf(fg, c, ig * ug);
    h = og * tanh_pade(c);
    out[(size_t)t * pstr + gid] = h;
  };

  // prologue: planes 0..7
#pragma unroll
  for (int p = 0; p < 8; ++p) wait_plane(p);
  float4 S0 = ld1(0), S1 = ld1(1), S2 = ld1(2), S3 = ld1(3);
  float4 S4 = ld1(4), S5 = ld1(5), S6 = ld1(6), S7 = ld1(7);

  int t = 0;
  for (; t + 16 <= T; t += 8) {
    // gate planes t+8 .. t+15 (consumed by this group's prefetches)
    wait_plane(t + 8);  wait_plane(t + 9);  wait_plane(t + 10); wait_plane(t + 11);
    wait_plane(t + 12); wait_plane(t + 13); wait_plane(t + 14); wait_plane(t + 15);
    { float4 zv = S0; S0 = ld1(t + 8);  step(zv, t);     }
    { float4 zv = S1; S1 = ld1(t + 9);  step(zv, t + 1); }
    { float4 zv = S2; S2 = ld1(t + 10); step(zv, t + 2); }
    { float4 zv = S3; S3 = ld1(t + 11); step(zv, t + 3); }
    { float4 zv = S4; S4 = ld1(t + 12); step(zv, t + 4); }
    { float4 zv = S5; S5 = ld1(t + 13); step(zv, t + 5); }
    { float4 zv = S6; S6 = ld1(t + 14); step(zv, t + 6); }
    { float4 zv = S7; S7 = ld1(t + 15); step(zv, t + 7); }
  }
  // tail: last 8 planes already in registers
  step(S0, t);     step(S1, t + 1); step(S2, t + 2); step(S3, t + 3);
  step(S4, t + 4); step(S5, t + 5); step(S6, t + 6); step(S7, t + 7);

  hx[gid]  = h;
  cxp[gid] = c;
}

// ---------------------------------------------------------------------------
// Fallback (shapes misalign or ws too small): fused single-thread-per-b.
// ---------------------------------------------------------------------------
struct GK {
  float wh[4][3][4];
  float ct1[4];
  float m2c[4];
};

__device__ __forceinline__ void load_gk(GK& K,
    const float* Wf, const float* Wi, const float* Wu, const float* Wo,
    const float* thf, const float* thi, const float* thu, const float* tho,
    int D)
{
  const float* Ws[4] = {Wf, Wi, Wu, Wo};
  const float* ts[4] = {thf, thi, thu, tho};
  const int ldw = D + 4;
#pragma unroll
  for (int g = 0; g < 4; ++g) {
#pragma unroll
    for (int jj = 0; jj < 3; ++jj) {
      int row = (jj == 2) ? 3 : jj;
#pragma unroll
      for (int qq = 0; qq < 4; ++qq)
        K.wh[g][jj][qq] = Ws[g][row * ldw + D + qq];
    }
    K.ct1[g] = fast_cos(ts[g][1]);
    K.m2c[g] = fast_cos(ts[g][2]);
  }
}

__device__ __forceinline__ void qlstm_step_sc(const float a[12], const GK& K,
                                              float h[4], float c[4])
{
  float gv[4][4];
#pragma unroll
  for (int g = 0; g < 4; ++g) {
    float m0 = fast_cos(a[g * 3 + 0]);
    float m1 = K.ct1[g] * fast_cos(a[g * 3 + 1]);
    float m3 = fast_cos(a[g * 3 + 2]);
    float m01 = m0 * m1;
    float m23 = K.m2c[g] * m3;
    gv[g][0] = m1 * m23;
    gv[g][1] = m01;
    gv[g][2] = m01 * K.m2c[g];
    gv[g][3] = m01 * m23;
  }
#pragma unroll
  for (int qq = 0; qq < 4; ++qq) {
    float fg = fast_sigmoid(gv[0][qq]);
    float ig = fast_sigmoid(gv[1][qq]);
    float ug = fast_tanh(gv[2][qq]);
    float og = fast_sigmoid(gv[3][qq]);
    c[qq] = fg * c[qq] + ig * ug;
    h[qq] = og * fast_tanh(c[qq]);
  }
}

__global__ __launch_bounds__(256) void qlstm_fused(
    const float* __restrict__ x,
    const float* __restrict__ Wf, const float* __restrict__ bf,
    const float* __restrict__ Wi, const float* __restrict__ bi,
    const float* __restrict__ Wu, const float* __restrict__ bu,
    const float* __restrict__ Wo, const float* __restrict__ bo,
    const float* __restrict__ thf, const float* __restrict__ thi,
    const float* __restrict__ thu, const float* __restrict__ tho,
    float* __restrict__ out, int T, int B, int D)
{
  int b = blockIdx.x * 256 + threadIdx.x;
  if (b >= B) return;
  GK K;
  load_gk(K, Wf, Wi, Wu, Wo, thf, thi, thu, tho, D);
  const float* Ws[4] = {Wf, Wi, Wu, Wo};
  const float* bs[4] = {bf, bi, bu, bo};
  const float* ts[4] = {thf, thi, thu, tho};
  const int ldw = D + 4;

  float base[12];
#pragma unroll
  for (int g = 0; g < 4; ++g) {
    base[g * 3 + 0] = bs[g][0] + ts[g][0];
    base[g * 3 + 1] = bs[g][1];
    base[g * 3 + 2] = bs[g][3] + ts[g][3];
  }

  float h[4] = {0.f, 0.f, 0.f, 0.f};
  float c[4] = {0.f, 0.f, 0.f, 0.f};
  float* hx  = out + (size_t)T * B * 4;
  float* cxp = hx + (size_t)B * 4;

  for (int t = 0; t < T; ++t) {
    float a[12];
#pragma unroll
    for (int j = 0; j < 12; ++j) a[j] = base[j];
    const float* xp = x + ((size_t)t * B + b) * D;
    for (int k = 0; k < D; k += 4) {
      float4 xv = *(const float4*)(xp + k);
#pragma unroll
      for (int g = 0; g < 4; ++g) {
        const float* W = Ws[g];
#pragma unroll
        for (int jj = 0; jj < 3; ++jj) {
          int row = (jj == 2) ? 3 : jj;
          const float* wp = W + row * ldw + k;
          a[g * 3 + jj] += xv.x * wp[0] + xv.y * wp[1] + xv.z * wp[2] + xv.w * wp[3];
        }
      }
    }
#pragma unroll
    for (int g = 0; g < 4; ++g) {
#pragma unroll
      for (int jj = 0; jj < 3; ++jj) {
        a[g * 3 + jj] += K.wh[g][jj][0] * h[0] + K.wh[g][jj][1] * h[1]
                       + K.wh[g][jj][2] * h[2] + K.wh[g][jj][3] * h[3];
      }
    }
    qlstm_step_sc(a, K, h, c);
    *(float4*)(out + ((size_t)t * B + b) * 4) = make_float4(h[0], h[1], h[2], h[3]);
  }
  *(float4*)(hx + (size_t)b * 4)  = make_float4(h[0], h[1], h[2], h[3]);
  *(float4*)(cxp + (size_t)b * 4) = make_float4(c[0], c[1], c[2], c[3]);
}

// ---------------------------------------------------------------------------
extern "C" void kernel_launch(void* const* d_in, const int* in_sizes, int n_in,
                              void* d_out, int out_size, void* d_ws, size_t ws_size,
                              hipStream_t stream)
{
  const float* x   = (const float*)d_in[0];
  const float* Wf  = (const float*)d_in[1];
  const float* bf  = (const float*)d_in[2];
  const float* Wi  = (const float*)d_in[3];
  const float* bi  = (const float*)d_in[4];
  const float* Wu  = (const float*)d_in[5];
  const float* bu  = (const float*)d_in[6];
  const float* Wo  = (const float*)d_in[7];
  const float* bo  = (const float*)d_in[8];
  const float* thf = (const float*)d_in[9];
  const float* thi = (const float*)d_in[10];
  const float* thu = (const float*)d_in[11];
  const float* tho = (const float*)d_in[12];

  int DH = in_sizes[1] / 4;                 // D + H (H = 4)
  int D  = DH - 4;                          // 128
  long long TB = (long long)in_sizes[0] / D;          // T*B
  int B = (int)(((long long)out_size - 4 * TB) / 8);  // out = 4*T*B + 8*B
  int T = (int)(TB / B);

  size_t zbytes = (size_t)TB * 16 * sizeof(float);
  size_t need   = zbytes + (size_t)T * sizeof(unsigned int);
  bool ok = (ws_size >= need) && ((D & 31) == 0) && ((B & 63) == 0) &&
            ((TB & 63) == 0) && ((T & 7) == 0) && (T >= 16);
  if (ok) {
    float* Z = (float*)d_ws;
    unsigned int* ctr = (unsigned int*)((char*)d_ws + zbytes);
    hipMemsetAsync(ctr, 0, (size_t)T * sizeof(unsigned int), stream);
    int nscan = (B * 4) / 64;            // scan blocks (1 wave each), first
    int ngemm = (int)(TB / 64);          // gemm blocks, after
    qlstm_fused_pc<<<nscan + ngemm, 64, 0, stream>>>(
        x, Wf, bf, Wi, bi, Wu, bu, Wo, bo, thf, thi, thu, tho,
        Z, ctr, (float*)d_out, TB, B, D, T, nscan);
  } else {
    qlstm_fused<<<(B + 255) / 256, 256, 0, stream>>>(x, Wf, bf, Wi, bi, Wu, bu, Wo, bo,
                                                     thf, thi, thu, tho,
                                                     (float*)d_out, T, B, D);
  }
}

// Round 15
// 87.904 us; speedup vs baseline: 4.1030x; 4.1030x over previous
//
#include <hip/hip_runtime.h>
#include <stdint.h>

// ---------------------------------------------------------------------------
// Fast math helpers.
// ---------------------------------------------------------------------------
__device__ __forceinline__ float fast_exp(float x) {
  return __builtin_amdgcn_exp2f(x * 1.4426950408889634f);
}
__device__ __forceinline__ float fast_rcp(float x) {
  return __builtin_amdgcn_rcpf(x);
}
__device__ __forceinline__ float fast_cos(float x) {
  // radians -> revolutions -> v_fract -> v_cos
  return __builtin_amdgcn_cosf(__builtin_amdgcn_fractf(x * 0.15915494309189535f));
}
// cos of an angle already expressed in REVOLUTIONS (pre-scaled upstream).
__device__ __forceinline__ float cos_rev(float x) {
  return __builtin_amdgcn_cosf(__builtin_amdgcn_fractf(x));
}
__device__ __forceinline__ float fast_sigmoid(float x) {
  return fast_rcp(1.0f + fast_exp(-x));
}
__device__ __forceinline__ float fast_tanh(float x) {
  return 1.0f - 2.0f * fast_rcp(1.0f + fast_exp(2.0f * x));
}
// sigmoid on [-1,1]: 0.5 + x/4 - x^3/48 + x^5/480 - 17x^7/80640 (err ~2e-5)
__device__ __forceinline__ float sigmoid_poly(float x) {
  float x2 = x * x;
  float p = fmaf(fmaf(fmaf(-2.1085373e-4f, x2, 2.0833334e-3f), x2,
                      -2.0833334e-2f), x2, 0.25f);
  return fmaf(x, p, 0.5f);
}
// tanh Pade(5,4): err <1e-6 @|x|<=1, <1.3e-4 @|x|<=2.5 (cell state bound ~2.1)
__device__ __forceinline__ float tanh_pade(float x) {
  float x2 = x * x;
  float num = x * fmaf(x2 + 105.f, x2, 945.f);
  float den = fmaf(fmaf(15.f, x2, 420.f), x2, 945.f);
  return num * fast_rcp(den);
}

// Cross-lane XOR exchange within each 4-lane quad via DPP quad_perm
// (update_dpp, tied-old operand — verified correct R7; ~4cy VALU).
template <int CTRL>
__device__ __forceinline__ float dppf(float v) {
  return __int_as_float(__builtin_amdgcn_update_dpp(
      0, __float_as_int(v), CTRL, 0xf, 0xf, true));
}
#define QP_XOR1 0xB1  // [1,0,3,2]
#define QP_XOR2 0x4E  // [2,3,0,1]
#define QP_XOR3 0x1B  // [3,2,1,0]

#define INV2PI 0.15915494309189535f

// ---------------------------------------------------------------------------
// Kernel 1: precompute x-part of gate activations.
//   Z layout: [t][b][gate][4], values in REVOLUTIONS (pre-scaled by 1/2pi so
//   the scan's cos needs no multiply).
//   value = (x[t,b,:] . W_g[row_j,:D] + fold)/2pi  (linear rows {0,1,3};
//   row 2 is dead: RZ on |0> is a global phase). fold = bias+theta (rows 0,3).
// Structure: R10's proven G64 (warm ~26us, near 21us one-pass HBM floor).
//  - 1-wave workgroups; padded [64][36] LDS tile: 0 bank conflicts.
//  - loads feed ds_write immediately (R4/R13: cross-barrier reg state spills).
//  - scalar FMA (R9: pk-FMA regressed; latency-bound not issue-bound).
// ---------------------------------------------------------------------------
__global__ __launch_bounds__(64) void qlstm_gemm(
    const float* __restrict__ x,
    const float* __restrict__ Wf, const float* __restrict__ bf,
    const float* __restrict__ Wi, const float* __restrict__ bi,
    const float* __restrict__ Wu, const float* __restrict__ bu,
    const float* __restrict__ Wo, const float* __restrict__ bo,
    const float* __restrict__ thf, const float* __restrict__ thi,
    const float* __restrict__ thu, const float* __restrict__ tho,
    float* __restrict__ Z, long long rows, int B, int D)
{
  __shared__ float tile[64][36];
  const long long base = (long long)blockIdx.x * 64;
  const int tid = threadIdx.x;  // 0..63
  const long long r = base + tid;
  const bool valid = r < rows;
  const int ldw = D + 4;
  const float* Ws[4] = {Wf, Wi, Wu, Wo};
  const float* bs[4] = {bf, bi, bu, bo};
  const float* ts[4] = {thf, thi, thu, tho};

  float acc[12];
#pragma unroll
  for (int g = 0; g < 4; ++g) {
    acc[g * 3 + 0] = bs[g][0] + ts[g][0];  // theta0 folded
    acc[g * 3 + 1] = bs[g][1];
    acc[g * 3 + 2] = bs[g][3] + ts[g][3];  // theta3 folded
  }

  const int nkc = D >> 5;  // D multiple of 32 (D=128)
  for (int kc = 0; kc < nkc; ++kc) {
    // stage 64 rows x 32 cols, coalesced (8 rows of 128B per instruction)
#pragma unroll
    for (int i = 0; i < 8; ++i) {
      int f = i * 64 + tid;
      int row = f >> 3, col = (f & 7) * 4;
      long long gr = base + row;
      if (gr < rows) {
        float4 v = *(const float4*)(x + gr * (long long)D + kc * 32 + col);
        *(float4*)&tile[row][col] = v;
      }
    }
    __syncthreads();  // 1-wave workgroup: near-free
    if (valid) {
#pragma unroll
      for (int k = 0; k < 32; k += 4) {
        float4 xv = *(float4*)&tile[tid][k];
#pragma unroll
        for (int g = 0; g < 4; ++g) {
#pragma unroll
          for (int jj = 0; jj < 3; ++jj) {
            int row2 = (jj == 2) ? 3 : jj;
            const float* wp = Ws[g] + row2 * ldw + kc * 32 + k;  // uniform -> s_load
            acc[g * 3 + jj] += xv.x * wp[0] + xv.y * wp[1] + xv.z * wp[2] + xv.w * wp[3];
          }
        }
      }
    }
    __syncthreads();
  }

  if (valid) {
    float* zp = Z + r * 16;  // [t][b][gate][4] layout, 64B per row
#pragma unroll
    for (int g = 0; g < 4; ++g) {
      *(float4*)(zp + g * 4) = make_float4(acc[g * 3 + 0] * INV2PI,
                                           acc[g * 3 + 1] * INV2PI,
                                           acc[g * 3 + 2] * INV2PI, 0.f);
    }
  }
}

// ---------------------------------------------------------------------------
// Kernel 2: scan, 4 lanes per batch element, TWO INDEPENDENT batch chains
// per lane (bA = base+quad, bB = bA+16). R12 proved the ~800cy/step is pure
// on-CU compute (LDS-fed inner loop with zero global loads was neutral);
// with 1 wave/SIMD the serial chain pays full dependent-issue latency on
// every link. Interleaving two independent chains fills the dep-stall slots
// (compiler list-scheduler interleaves the two inlined step bodies).
// Angles arrive in revolutions (no per-cos multiply). Cross-lane: DPP
// quad_perm (verified R7). Depth-4 named prefetch per chain.
// ---------------------------------------------------------------------------
__global__ __launch_bounds__(64) void qlstm_scan4x2(
    const float* __restrict__ Z,
    const float* __restrict__ Wf, const float* __restrict__ Wi,
    const float* __restrict__ Wu, const float* __restrict__ Wo,
    const float* __restrict__ thf, const float* __restrict__ thi,
    const float* __restrict__ thu, const float* __restrict__ tho,
    float* __restrict__ out, int T, int B, int D)
{
  const int tid = threadIdx.x;
  const int quad = tid >> 2, q = tid & 3;
  const int bA = blockIdx.x * 32 + quad;  // wave covers b in [base, base+32)
  const int bB = bA + 16;
  if (bB >= B) return;  // launcher guarantees B % 32 == 0

  const float* Wg = (q == 0) ? Wf : (q == 1) ? Wi : (q == 2) ? Wu : Wo;
  const float* th = (q == 0) ? thf : (q == 1) ? thi : (q == 2) ? thu : tho;
  const int ldw = D + 4;
  const float ct1 = fast_cos(th[1]);  // init-only, radians path
  const float m2c = fast_cos(th[2]);

  // wh in REVOLUTIONS; wh[jj][d] pairs with h from lane q^d.
  float wh[3][4];
#pragma unroll
  for (int jj = 0; jj < 3; ++jj) {
    int row = (jj == 2) ? 3 : jj;
#pragma unroll
    for (int d = 0; d < 4; ++d)
      wh[jj][d] = Wg[row * ldw + D + (q ^ d)] * INV2PI;
  }
  const bool e0 = ((q & 1) == 0);
  const bool e1 = ((q & 2) == 0);

  float hA = 0.f, cA = 0.f, hB = 0.f, cB = 0.f;

  const size_t tstr = (size_t)16 * B;  // Z floats per time step
  const size_t pstr = (size_t)4 * B;   // out floats per time step
  const size_t slotA = (size_t)(bA * 4 + q);
  const size_t slotB = (size_t)(bB * 4 + q);
  const float* ZA = Z + slotA * 4;
  const float* ZB = Z + slotB * 4;
  float* hx  = out + (size_t)T * B * 4;
  float* cxp = hx + (size_t)B * 4;

  auto ldA = [&](int t) -> float4 { return *(const float4*)(ZA + (size_t)t * tstr); };
  auto ldB = [&](int t) -> float4 { return *(const float4*)(ZB + (size_t)t * tstr); };

  auto step = [&](float4 zv, float& h, float& c, size_t oidx) {
    float z0 = zv.x, z1 = zv.y, z2 = zv.z;  // revolutions
    float h1 = dppf<QP_XOR1>(h);
    float h2 = dppf<QP_XOR2>(h);
    float h3 = dppf<QP_XOR3>(h);
    float a0 = fmaf(wh[0][0], h, fmaf(wh[0][1], h1, fmaf(wh[0][2], h2, fmaf(wh[0][3], h3, z0))));
    float a1 = fmaf(wh[1][0], h, fmaf(wh[1][1], h1, fmaf(wh[1][2], h2, fmaf(wh[1][3], h3, z1))));
    float a2 = fmaf(wh[2][0], h, fmaf(wh[2][1], h1, fmaf(wh[2][2], h2, fmaf(wh[2][3], h3, z2))));
    float m0 = cos_rev(a0);
    float m1 = ct1 * cos_rev(a1);
    float m3 = cos_rev(a2);
    float m01 = m0 * m1, m23 = m2c * m3;
    float g0 = m1 * m23;        // <Z0> = m1 m2 m3
    float g1 = m01;             // <Z1> = m0 m1
    float g2 = m01 * m2c;       // <Z2> = m0 m1 m2
    float g3 = m01 * m23;       // <Z3> = m0 m1 m2 m3
    // 4x4 quad transpose (two XOR stages); after: w_r = gate r's component q.
    float x0 = dppf<QP_XOR1>(g0);
    float x1 = dppf<QP_XOR1>(g1);
    float x2 = dppf<QP_XOR1>(g2);
    float x3 = dppf<QP_XOR1>(g3);
    float s0 = e0 ? g0 : x1;
    float s1 = e0 ? x0 : g1;
    float s2 = e0 ? g2 : x3;
    float s3 = e0 ? x2 : g3;
    float y0 = dppf<QP_XOR2>(s0);
    float y1 = dppf<QP_XOR2>(s1);
    float y2 = dppf<QP_XOR2>(s2);
    float y3 = dppf<QP_XOR2>(s3);
    float wf_ = e1 ? s0 : y2;
    float wi_ = e1 ? s1 : y3;
    float wu_ = e1 ? y0 : s2;
    float wo_ = e1 ? y1 : s3;
    // gates (|input| <= 1: products of cosines)
    float fg = sigmoid_poly(wf_);
    float ig = sigmoid_poly(wi_);
    float ug = tanh_pade(wu_);
    float og = sigmoid_poly(wo_);
    c = fmaf(fg, c, ig * ug);
    h = og * tanh_pade(c);
    out[oidx] = h;
  };

  // depth-4 named prefetch per chain (rule #20: no runtime-indexed arrays)
  float4 A0, A1, A2, A3, Bb0, Bb1, Bb2, Bb3;
  if (T > 0) { A0 = ldA(0); Bb0 = ldB(0); }
  if (T > 1) { A1 = ldA(1); Bb1 = ldB(1); }
  if (T > 2) { A2 = ldA(2); Bb2 = ldB(2); }
  if (T > 3) { A3 = ldA(3); Bb3 = ldB(3); }

  int T4 = T & ~3;
  for (int t = 0; t < T4; t += 4) {
    { float4 za = A0, zb = Bb0;
      if (t + 4 < T) { A0 = ldA(t + 4); Bb0 = ldB(t + 4); }
      size_t o = (size_t)t * pstr;
      step(za, hA, cA, o + slotA); step(zb, hB, cB, o + slotB); }
    { float4 za = A1, zb = Bb1;
      if (t + 5 < T) { A1 = ldA(t + 5); Bb1 = ldB(t + 5); }
      size_t o = (size_t)(t + 1) * pstr;
      step(za, hA, cA, o + slotA); step(zb, hB, cB, o + slotB); }
    { float4 za = A2, zb = Bb2;
      if (t + 6 < T) { A2 = ldA(t + 6); Bb2 = ldB(t + 6); }
      size_t o = (size_t)(t + 2) * pstr;
      step(za, hA, cA, o + slotA); step(zb, hB, cB, o + slotB); }
    { float4 za = A3, zb = Bb3;
      if (t + 7 < T) { A3 = ldA(t + 7); Bb3 = ldB(t + 7); }
      size_t o = (size_t)(t + 3) * pstr;
      step(za, hA, cA, o + slotA); step(zb, hB, cB, o + slotB); }
  }
  for (int t = T4; t < T; ++t) {
    size_t o = (size_t)t * pstr;
    step(ldA(t), hA, cA, o + slotA);
    step(ldB(t), hB, cB, o + slotB);
  }

  hx[slotA]  = hA;  hx[slotB]  = hB;
  cxp[slotA] = cA;  cxp[slotB] = cB;
}

// ---------------------------------------------------------------------------
// Fallback (shapes misalign or ws too small): fused single-thread-per-b.
// ---------------------------------------------------------------------------
struct GK {
  float wh[4][3][4];
  float ct1[4];
  float m2c[4];
};

__device__ __forceinline__ void load_gk(GK& K,
    const float* Wf, const float* Wi, const float* Wu, const float* Wo,
    const float* thf, const float* thi, const float* thu, const float* tho,
    int D)
{
  const float* Ws[4] = {Wf, Wi, Wu, Wo};
  const float* ts[4] = {thf, thi, thu, tho};
  const int ldw = D + 4;
#pragma unroll
  for (int g = 0; g < 4; ++g) {
#pragma unroll
    for (int jj = 0; jj < 3; ++jj) {
      int row = (jj == 2) ? 3 : jj;
#pragma unroll
      for (int qq = 0; qq < 4; ++qq)
        K.wh[g][jj][qq] = Ws[g][row * ldw + D + qq];
    }
    K.ct1[g] = fast_cos(ts[g][1]);
    K.m2c[g] = fast_cos(ts[g][2]);
  }
}

__device__ __forceinline__ void qlstm_step_sc(const float a[12], const GK& K,
                                              float h[4], float c[4])
{
  float gv[4][4];
#pragma unroll
  for (int g = 0; g < 4; ++g) {
    float m0 = fast_cos(a[g * 3 + 0]);
    float m1 = K.ct1[g] * fast_cos(a[g * 3 + 1]);
    float m3 = fast_cos(a[g * 3 + 2]);
    float m01 = m0 * m1;
    float m23 = K.m2c[g] * m3;
    gv[g][0] = m1 * m23;
    gv[g][1] = m01;
    gv[g][2] = m01 * K.m2c[g];
    gv[g][3] = m01 * m23;
  }
#pragma unroll
  for (int qq = 0; qq < 4; ++qq) {
    float fg = fast_sigmoid(gv[0][qq]);
    float ig = fast_sigmoid(gv[1][qq]);
    float ug = fast_tanh(gv[2][qq]);
    float og = fast_sigmoid(gv[3][qq]);
    c[qq] = fg * c[qq] + ig * ug;
    h[qq] = og * fast_tanh(c[qq]);
  }
}

__global__ __launch_bounds__(256) void qlstm_fused(
    const float* __restrict__ x,
    const float* __restrict__ Wf, const float* __restrict__ bf,
    const float* __restrict__ Wi, const float* __restrict__ bi,
    const float* __restrict__ Wu, const float* __restrict__ bu,
    const float* __restrict__ Wo, const float* __restrict__ bo,
    const float* __restrict__ thf, const float* __restrict__ thi,
    const float* __restrict__ thu, const float* __restrict__ tho,
    float* __restrict__ out, int T, int B, int D)
{
  int b = blockIdx.x * 256 + threadIdx.x;
  if (b >= B) return;
  GK K;
  load_gk(K, Wf, Wi, Wu, Wo, thf, thi, thu, tho, D);
  const float* Ws[4] = {Wf, Wi, Wu, Wo};
  const float* bs[4] = {bf, bi, bu, bo};
  const float* ts[4] = {thf, thi, thu, tho};
  const int ldw = D + 4;

  float base[12];
#pragma unroll
  for (int g = 0; g < 4; ++g) {
    base[g * 3 + 0] = bs[g][0] + ts[g][0];
    base[g * 3 + 1] = bs[g][1];
    base[g * 3 + 2] = bs[g][3] + ts[g][3];
  }

  float h[4] = {0.f, 0.f, 0.f, 0.f};
  float c[4] = {0.f, 0.f, 0.f, 0.f};
  float* hx  = out + (size_t)T * B * 4;
  float* cxp = hx + (size_t)B * 4;

  for (int t = 0; t < T; ++t) {
    float a[12];
#pragma unroll
    for (int j = 0; j < 12; ++j) a[j] = base[j];
    const float* xp = x + ((size_t)t * B + b) * D;
    for (int k = 0; k < D; k += 4) {
      float4 xv = *(const float4*)(xp + k);
#pragma unroll
      for (int g = 0; g < 4; ++g) {
        const float* W = Ws[g];
#pragma unroll
        for (int jj = 0; jj < 3; ++jj) {
          int row = (jj == 2) ? 3 : jj;
          const float* wp = W + row * ldw + k;
          a[g * 3 + jj] += xv.x * wp[0] + xv.y * wp[1] + xv.z * wp[2] + xv.w * wp[3];
        }
      }
    }
#pragma unroll
    for (int g = 0; g < 4; ++g) {
#pragma unroll
      for (int jj = 0; jj < 3; ++jj) {
        a[g * 3 + jj] += K.wh[g][jj][0] * h[0] + K.wh[g][jj][1] * h[1]
                       + K.wh[g][jj][2] * h[2] + K.wh[g][jj][3] * h[3];
      }
    }
    qlstm_step_sc(a, K, h, c);
    *(float4*)(out + ((size_t)t * B + b) * 4) = make_float4(h[0], h[1], h[2], h[3]);
  }
  *(float4*)(hx + (size_t)b * 4)  = make_float4(h[0], h[1], h[2], h[3]);
  *(float4*)(cxp + (size_t)b * 4) = make_float4(c[0], c[1], c[2], c[3]);
}

// ---------------------------------------------------------------------------
extern "C" void kernel_launch(void* const* d_in, const int* in_sizes, int n_in,
                              void* d_out, int out_size, void* d_ws, size_t ws_size,
                              hipStream_t stream)
{
  const float* x   = (const float*)d_in[0];
  const float* Wf  = (const float*)d_in[1];
  const float* bf  = (const float*)d_in[2];
  const float* Wi  = (const float*)d_in[3];
  const float* bi  = (const float*)d_in[4];
  const float* Wu  = (const float*)d_in[5];
  const float* bu  = (const float*)d_in[6];
  const float* Wo  = (const float*)d_in[7];
  const float* bo  = (const float*)d_in[8];
  const float* thf = (const float*)d_in[9];
  const float* thi = (const float*)d_in[10];
  const float* thu = (const float*)d_in[11];
  const float* tho = (const float*)d_in[12];

  int DH = in_sizes[1] / 4;                 // D + H (H = 4)
  int D  = DH - 4;                          // 128
  long long TB = (long long)in_sizes[0] / D;          // T*B
  int B = (int)(((long long)out_size - 4 * TB) / 8);  // out = 4*T*B + 8*B
  int T = (int)(TB / B);

  size_t zbytes = (size_t)TB * 16 * sizeof(float);
  bool ok = (ws_size >= zbytes) && ((D & 31) == 0) && ((B & 31) == 0) &&
            ((TB & 63) == 0);
  if (ok) {
    float* Z = (float*)d_ws;
    int gblocks = (int)(TB / 64);
    qlstm_gemm<<<gblocks, 64, 0, stream>>>(x, Wf, bf, Wi, bi, Wu, bu, Wo, bo,
                                           thf, thi, thu, tho, Z, TB, B, D);
    int sblocks = B / 32;
    qlstm_scan4x2<<<sblocks, 64, 0, stream>>>(Z, Wf, Wi, Wu, Wo,
                                              thf, thi, thu, tho,
                                              (float*)d_out, T, B, D);
  } else {
    qlstm_fused<<<(B + 255) / 256, 256, 0, stream>>>(x, Wf, bf, Wi, bi, Wu, bu, Wo, bo,
                                                     thf, thi, thu, tho,
                                                     (float*)d_out, T, B, D);
  }
}